// Round 6
// baseline (1424.279 us; speedup 1.0000x reference)
//
#include <hip/hip_runtime.h>
#include <stdint.h>

// Problem constants
#define BATCH 128
#define LFULL 4096
#define TT 48            // number of tags
#define NPOT 4094        // pot timesteps (L-2)
#define NBP  4093        // number of bp entries / stored state vectors
#define SEG  64          // backtrack segment length
#define NSEG 64          // ceil(NBP/SEG)
#define SLOT 192         // bytes per state slot (48 floats)

// ---------------------------------------------------------------------------
// K1: forward Viterbi scan (values only, no argmax). One wave per batch,
// one wave per block (128 blocks). Critical-path design:
//  - tcol[48] (transition column kk) pinned in VGPRs via opaque asm: the
//    allocator may NOT rematerialize it from memory (R0 re-read it from LDS
//    every step, R4 from global -- both doubled the serial chain).
//  - Double-buffered LDS state (lsw[2][64]): step t reads lsw[p], writes
//    lsw[p^1]. Per-wave LDS ops execute in order, so NO barriers are needed
//    anywhere in the loop; the compiler's fine-grained lgkmcnt handles the
//    register dependencies.
//  - Reads are uniform-address (all lanes read the same 16B) -> broadcast,
//    bank-conflict-free.
//  - max3-shaped reduction tree (47 fmax, fusable to ~24 v_max3_f32).
// Stores state vectors s_0..s_4092 into the pot region of d_out (scratch).
// Also writes last_tag (byte) into bound[b][NSEG].
__global__ __launch_bounds__(64, 1) void k_forward(const float* __restrict__ in,
                                                   const float* __restrict__ trans,
                                                   char* __restrict__ statesBase,
                                                   unsigned char* __restrict__ bound) {
    const int b = blockIdx.x;
    const int lane = threadIdx.x;
    const int kk = (lane < TT) ? lane : 0;

    __shared__ __align__(16) float lsw[2][64];   // ping/pong state (48 used)

    // tcol[j] = T[j][kk]; coalesced load (lanes consecutive for fixed j),
    // then pinned opaque so it stays resident in 48 VGPRs.
    float tcol[TT];
#pragma unroll
    for (int j = 0; j < TT; ++j) tcol[j] = trans[j * TT + kk];
#pragma unroll
    for (int j = 0; j < TT; ++j) asm volatile("" : "+v"(tcol[j]));

    const float* inb = in + (size_t)b * (LFULL * TT);
    char* sb = statesBase + (size_t)b * NBP * SLOT;

    // s0 = pot[b,0,:] = in[b,1,:]
    float s0 = inb[TT + kk];
    lsw[0][lane] = s0;                         // lanes 48-63 write junk, never read
    if (lane < TT) ((float*)sb)[lane] = s0;    // store s_0 (slot 0)

    // one Viterbi step: snew[k] = max_j(s[j]+T[j][k]) + e.
    // Reads lsw[P], writes lsw[P^1]. P is a literal at every call site.
    auto STEP = [&](int P, int t, float e, bool snap) {
        float c[TT];
#pragma unroll
        for (int j = 0; j < 12; ++j) {
            float4 v = *(const float4*)(&lsw[P][4 * j]);
            c[4*j+0] = v.x + tcol[4*j+0];
            c[4*j+1] = v.y + tcol[4*j+1];
            c[4*j+2] = v.z + tcol[4*j+2];
            c[4*j+3] = v.w + tcol[4*j+3];
        }
        float r[16];
#pragma unroll
        for (int g = 0; g < 16; ++g)
            r[g] = fmaxf(fmaxf(c[3*g], c[3*g+1]), c[3*g+2]);
        float u0 = fmaxf(fmaxf(r[0], r[1]), r[2]);
        float u1 = fmaxf(fmaxf(r[3], r[4]), r[5]);
        float u2 = fmaxf(fmaxf(r[6], r[7]), r[8]);
        float u3 = fmaxf(fmaxf(r[9], r[10]), r[11]);
        float u4 = fmaxf(fmaxf(r[12], r[13]), r[14]);
        float u5 = fmaxf(r[15], u0);
        float w0 = fmaxf(fmaxf(u1, u2), u3);
        float w1 = fmaxf(u4, u5);
        float snew = fmaxf(w0, w1) + e;
        lsw[P ^ 1][lane] = snew;               // unconditional write
        if (snap && lane < TT)                 // snapshot s_t (fire-and-forget)
            *(float*)(sb + (size_t)t * SLOT + (size_t)lane * 4) = snew;
    };

    // emission for step t is pot[b,t,:] = in[b,t+1,:]; clamp keeps the
    // address valid (no exec-mask) — over-read values are never used.
    auto LD = [&](int t) -> float {
        int tc = (t <= NBP) ? t : NBP;
        return inb[(size_t)(tc + 1) * TT + kk];
    };

    float e0 = LD(1), e1 = LD(2), e2 = LD(3), e3 = LD(4);
    float e4 = LD(5), e5 = LD(6), e6 = LD(7), e7 = LD(8);
    int t = 1;
    for (; t + 7 <= NBP; t += 8) {             // t = 1, 9, ..., 4081 (odd)
        STEP(0, t,     e0, true); e0 = LD(t + 8);
        STEP(1, t + 1, e1, true); e1 = LD(t + 9);
        STEP(0, t + 2, e2, true); e2 = LD(t + 10);
        STEP(1, t + 3, e3, true); e3 = LD(t + 11);
        STEP(0, t + 4, e4, true); e4 = LD(t + 12);
        STEP(1, t + 5, e5, true); e5 = LD(t + 13);
        STEP(0, t + 6, e6, true); e6 = LD(t + 14);
        STEP(1, t + 7, e7, true); e7 = LD(t + 15);
    }
    // remainder: t = 4089..4093 (5 steps, starts with src = buffer 0)
    STEP(0, 4089, e0, true);
    STEP(1, 4090, e1, true);
    STEP(0, 4091, e2, true);
    STEP(1, 4092, e3, true);
    STEP(0, 4093, e4, false);                  // final state lands in lsw[1]

    // last_tag = first-index argmax of final state
    if (lane == 0) {
        float best = lsw[1][0]; int bi = 0;
#pragma unroll
        for (int j = 1; j < TT; ++j) {
            float v = lsw[1][j];
            if (v > best) { best = v; bi = j; }
        }
        bound[b * (NSEG + 1) + NSEG] = (unsigned char)bi;
    }
}

// ---------------------------------------------------------------------------
// K2: recompute backpointers bp_i[k] = argmax_j(s_i[j] + T[j][k]) for ALL
// (b,i,k), massively parallel. One wave per (b, chunk of 16 i's). bp bytes
// overwrite the first 48 bytes of each state slot (slot owned by this wave,
// fully read before written).
#define CHUNK 16
__global__ __launch_bounds__(256) void k_bp(const float* __restrict__ trans,
                                            char* __restrict__ statesBase) {
    const int lane = threadIdx.x & 63;
    const int wv = threadIdx.x >> 6;
    const int b = blockIdx.y * 4 + wv;
    const int i0 = blockIdx.x * CHUNK;
    const int kk = (lane < TT) ? lane : 0;

    __shared__ float ldsT[TT * TT];
    for (int i = threadIdx.x; i < TT * TT; i += 256) ldsT[i] = trans[i];
    __syncthreads();

    float tcol[TT];
#pragma unroll
    for (int j = 0; j < TT; ++j) tcol[j] = ldsT[j * TT + kk];

    char* sb = statesBase + (size_t)b * NBP * SLOT;

    for (int ii = 0; ii < CHUNK; ++ii) {
        int i = i0 + ii;
        if (i >= NBP) break;                     // uniform across wave
        const float* sp = (const float*)(sb + (size_t)i * SLOT);
        float sv[TT];
#pragma unroll
        for (int j = 0; j < TT; j += 4) {
            float4 v = *(const float4*)(sp + j);
            sv[j] = v.x; sv[j+1] = v.y; sv[j+2] = v.z; sv[j+3] = v.w;
        }
        float best = sv[0] + tcol[0]; int bi = 0;
#pragma unroll
        for (int j = 1; j < TT; ++j) {
            float v = sv[j] + tcol[j];
            if (v > best) { best = v; bi = j; }  // strict > : first-index wins
        }
        if (lane < TT)
            *(unsigned char*)(sb + (size_t)i * SLOT + lane) = (unsigned char)bi;
    }
}

// ---------------------------------------------------------------------------
// K3: compose each 64-step segment of backpointer maps into one map G_s
// (tag at segment end -> tag at segment start). Lane x traces start value x.
__global__ __launch_bounds__(64) void k_compose(const char* __restrict__ statesBase,
                                                unsigned char* __restrict__ G) {
    const int s = blockIdx.x, b = blockIdx.y;
    const int i0 = s * SEG;
    const int cnt = (SEG < NBP - i0) ? SEG : (NBP - i0);
    const int lane = threadIdx.x;

    __shared__ unsigned char lbp[SEG * TT];
    const char* sb = statesBase + (size_t)b * NBP * SLOT;
    for (int ii = 0; ii < cnt; ++ii) {
        if (lane < 12)
            ((uint32_t*)lbp)[ii * 12 + lane] =
                *(const uint32_t*)(sb + (size_t)(i0 + ii) * SLOT + (size_t)lane * 4);
    }
    __syncthreads();

    if (lane < TT) {
        int M = lane;
        for (int ii = cnt - 1; ii >= 0; --ii) M = lbp[ii * TT + M];
        G[(b * NSEG + s) * TT + lane] = (unsigned char)M;
    }
}

// ---------------------------------------------------------------------------
// K4: chain across segments: boundary tag at each segment start.
__global__ void k_boundary(const unsigned char* __restrict__ G,
                           unsigned char* __restrict__ bound) {
    int b = threadIdx.x;                 // 128 threads, 1 block
    int x = bound[b * (NSEG + 1) + NSEG];
    for (int s = NSEG - 1; s >= 0; --s) {
        x = G[(b * NSEG + s) * TT + x];
        bound[b * (NSEG + 1) + s] = x;
    }
}

// ---------------------------------------------------------------------------
// K5: fill tags within each segment by re-walking its bp maps from the known
// entering boundary tag. Writes final float tags.
__global__ __launch_bounds__(64) void k_fill(const char* __restrict__ statesBase,
                                             const unsigned char* __restrict__ bound,
                                             float* __restrict__ tags) {
    const int s = blockIdx.x, b = blockIdx.y;
    const int i0 = s * SEG;
    const int cnt = (SEG < NBP - i0) ? SEG : (NBP - i0);
    const int lane = threadIdx.x;

    __shared__ unsigned char lbp[SEG * TT];
    const char* sb = statesBase + (size_t)b * NBP * SLOT;
    for (int ii = 0; ii < cnt; ++ii) {
        if (lane < 12)
            ((uint32_t*)lbp)[ii * 12 + lane] =
                *(const uint32_t*)(sb + (size_t)(i0 + ii) * SLOT + (size_t)lane * 4);
    }
    __syncthreads();

    if (lane == 0) {
        int x = bound[b * (NSEG + 1) + s + 1];   // tag at position (s+1)*SEG (or last_tag)
        if (s == NSEG - 1)
            tags[(size_t)b * NPOT + (NPOT - 1)] = (float)x;
        for (int ii = cnt - 1; ii >= 0; --ii) {
            x = lbp[ii * TT + x];
            tags[(size_t)b * NPOT + i0 + ii] = (float)x;
        }
    }
}

// ---------------------------------------------------------------------------
// K6: final copies — pot = in[:,1:-1,:] and transitions passthrough.
__global__ __launch_bounds__(256) void k_copy(const float* __restrict__ in,
                                              const float* __restrict__ trans,
                                              float* __restrict__ out) {
    const int potN4 = (BATCH * NPOT * TT) / 4;   // 6,288,384 float4s
    const int rowN = NPOT * TT;                  // 196,512
    int idx = blockIdx.x * 256 + threadIdx.x;
    if (idx < potN4) {
        int p4 = idx * 4;
        int b = p4 / rowN;
        int off = p4 - b * rowN;
        float4 v = *(const float4*)(in + (size_t)b * (LFULL * TT) + off + TT);
        *(float4*)(out + p4) = v;
    } else if (idx < potN4 + (TT * TT) / 4) {
        int q = idx - potN4;
        *(float4*)(out + (size_t)BATCH * NPOT * TT + (size_t)q * 4) =
            *(const float4*)(trans + (size_t)q * 4);
    }
}

// ---------------------------------------------------------------------------
extern "C" void kernel_launch(void* const* d_in, const int* in_sizes, int n_in,
                              void* d_out, int out_size, void* d_ws, size_t ws_size,
                              hipStream_t stream) {
    (void)in_sizes; (void)n_in; (void)d_ws; (void)ws_size; (void)out_size;

    const float* in = (const float*)d_in[0];
    const float* trans = (const float*)d_in[1];
    float* out = (float*)d_out;

    // Scratch carved out of d_out (stream-ordered so everything is rewritten):
    //  - pot region   [0 .. 100.6MB): state vectors, then bp bytes in-place
    //  - trans region [2304 floats]: boundary tags (128 x 65 bytes)
    //  - tags region  [524032 floats]: segment maps G, then final tags
    char* statesBase = (char*)d_out;
    unsigned char* bound = (unsigned char*)(out + (size_t)BATCH * NPOT * TT);
    unsigned char* G = (unsigned char*)(out + (size_t)BATCH * NPOT * TT + TT * TT);
    float* tags = out + (size_t)BATCH * NPOT * TT + TT * TT;

    k_forward <<<dim3(BATCH),        dim3(64),  0, stream>>>(in, trans, statesBase, bound);
    k_bp      <<<dim3(256, 32),      dim3(256), 0, stream>>>(trans, statesBase);
    k_compose <<<dim3(NSEG, BATCH),  dim3(64),  0, stream>>>(statesBase, G);
    k_boundary<<<dim3(1),            dim3(BATCH), 0, stream>>>(G, bound);
    k_fill    <<<dim3(NSEG, BATCH),  dim3(64),  0, stream>>>(statesBase, bound, tags);

    int total4 = (BATCH * NPOT * TT) / 4 + (TT * TT) / 4;
    k_copy    <<<dim3((total4 + 255) / 256), dim3(256), 0, stream>>>(in, trans, out);
}